// Round 4
// baseline (143.241 us; speedup 1.0000x reference)
//
#include <hip/hip_runtime.h>
#include <stdint.h>

#define BATCH 256
#define IDIM  8192
#define ODIM  8192
#define MS    64
#define IC    128
#define OC    128
#define NB    1024

// GEMM geometry: 256x256 tile, BK=64, 8 waves (2M x 4N), wave tile 128x64
#define BM 256
#define BN 256
#define BK 64
#define KSPLIT 8
#define KT (IC / KSPLIT)           // 16 K-tiles per workgroup

// dynamic LDS layout: A dbuf 2 x 32KB, B ring-3 3 x 32KB = 160 KB (byte offsets)
#define ABYTE(s) ((s) * 32768u)
#define BBYTE(s) (65536u + (s) * 32768u)

typedef __bf16 bf16x8 __attribute__((ext_vector_type(8)));
typedef float  floatx4 __attribute__((ext_vector_type(4)));

// s_waitcnt imm: vmcnt[3:0]|[15:14], expcnt/lgkmcnt = don't-care
#define WAITCNT_VM(n) ((((n) & 15) | (((n) >> 4) << 14)) | 0x70 | 0xF00)

__device__ __forceinline__ void async_load16(unsigned short* lds_p, const unsigned short* g_p) {
    __builtin_amdgcn_global_load_lds(
        (const __attribute__((address_space(1))) unsigned int*)g_p,
        (__attribute__((address_space(3))) unsigned int*)lds_p,
        16, 0, 0);
}

__device__ __forceinline__ unsigned short f32_to_bf16(float f) {
    unsigned int u = __float_as_uint(f);
    u += 0x7FFFu + ((u >> 16) & 1u);
    return (unsigned short)(u >> 16);
}

// ---- kernel 1: blocks -> bf16 [b][c][r] | x -> bf16 row-major | parts -> pT[ob][ib] ----
#define XCONV_BLKS 1024
#define PT_BLKS 64
__global__ void k_convert(const float* __restrict__ x, const float* __restrict__ blocks,
                          const int* __restrict__ parts,
                          unsigned short* __restrict__ xb, unsigned short* __restrict__ bt,
                          int* __restrict__ pT) {
    __shared__ float tile[MS][MS + 1];
    int b = blockIdx.x;
    if (b < NB) {
        const float4* src4 = (const float4*)(blocks + (size_t)b * MS * MS);
        unsigned short* dst = bt + (size_t)b * MS * MS;
        #pragma unroll
        for (int i = 0; i < 4; ++i) {
            int slot = i * 256 + threadIdx.x;
            int r = slot >> 4, c4 = (slot & 15) * 4;
            float4 v = src4[slot];
            tile[r][c4 + 0] = v.x; tile[r][c4 + 1] = v.y;
            tile[r][c4 + 2] = v.z; tile[r][c4 + 3] = v.w;
        }
        __syncthreads();
        #pragma unroll
        for (int i = 0; i < 2; ++i) {
            int slot = i * 256 + threadIdx.x;
            int c = slot >> 3, o = slot & 7;
            union { unsigned short s[8]; uint4 v; } u;
            #pragma unroll
            for (int j = 0; j < 8; ++j) u.s[j] = f32_to_bf16(tile[o * 8 + j][c]);
            *(uint4*)(dst + c * MS + o * 8) = u.v;        // bt[b][c][r]
        }
    } else if (b < NB + XCONV_BLKS) {
        int t = (b - NB) * 256 + threadIdx.x;
        const float4* x4 = (const float4*)x;
        float4 a = x4[2 * t], bb = x4[2 * t + 1];
        union { unsigned short s[8]; uint4 v; } u;
        u.s[0] = f32_to_bf16(a.x);  u.s[1] = f32_to_bf16(a.y);
        u.s[2] = f32_to_bf16(a.z);  u.s[3] = f32_to_bf16(a.w);
        u.s[4] = f32_to_bf16(bb.x); u.s[5] = f32_to_bf16(bb.y);
        u.s[6] = f32_to_bf16(bb.z); u.s[7] = f32_to_bf16(bb.w);
        ((uint4*)xb)[t] = u.v;
    } else {
        int t = (b - NB - XCONV_BLKS) * 256 + threadIdx.x;   // 16384
        int oc = t >> 7, ic = t & 127;
        pT[t] = parts[ic * OC + oc];                          // pT[ob][ib]
    }
}

// ---- kernel 2: GEMM 256x256, 8 waves, wave tile 128x64. A dbuf(2) + B ring(3).
//      m201-faithful 4-phase schedule per K-tile. Each phase:
//        {asm ds_read burst (A4 [+B4]) ; stage -> s_barrier -> lgkmcnt(0) ->
//         sched_barrier(0) -> setprio(1) 16xMFMA setprio(0) -> s_barrier}
//      Overlap mechanism: MFMA cluster issues in ~80cyc and backlogs the matrix
//      pipe; waves pass the post-barrier and execute the NEXT phase's ds_reads
//      under that backlog. Counted vmcnt(4) only at tile boundaries:
//      queue = [B(t+1)x4, A(t+1)x4, B(t+2)x4] -> retires exactly tile t+1 needs.
//      LDS XOR swizzle (verified 0 conflicts): LDS[r][oct] = global[r][oct ^ (r&7)]
extern __shared__ unsigned short smem[];   // 160 KB dynamic

__global__ __launch_bounds__(512, 2)
void k_mosaic_gemm(const unsigned short* __restrict__ xb,
                   const unsigned short* __restrict__ bt,
                   const int* __restrict__ pT,
                   float* __restrict__ partial) {
    const int tid  = threadIdx.x;
    const int lane = tid & 63;
    const int wave = tid >> 6;
    const int wrow = wave >> 2;      // 0..1 : 128-row band
    const int wcol = wave & 3;       // 0..3 : 64-col band
    const int ks = blockIdx.x;       // 0..7  (linear%8 -> one K-split per XCD)
    const int nt = blockIdx.y;       // 0..31

    const int ob0 = nt * 4;          // 4 output-blocks per 256-col tile
    const int kb0 = ks * KT;         // global K-tile base (0..127 step 16)

    const int row  = lane & 15;
    const int quad = lane >> 4;

    // all 4 ob x 16 ib part indices for this WG, one per lane (quad=ob, row=ib)
    int pv = pT[(ob0 + quad) * IC + kb0 + row];

    // frag BYTE offsets (within a 32KB stage): elem = rbase*64 + swz octet*8
    const int swz0 = ((quad)     ^ (row & 7)) << 3;    // kk0: octets 0..3
    const int swz1 = ((quad + 4) ^ (row & 7)) << 3;    // kk1: octets 4..7
    const unsigned a_b0 = 2u * ((wrow * 128 + row) * MS + swz0);
    const unsigned a_b1 = 2u * ((wrow * 128 + row) * MS + swz1);
    const unsigned b_b0 = 2u * ((wcol * 64 + row) * MS + swz0);
    const unsigned b_b1 = 2u * ((wcol * 64 + row) * MS + swz1);
    const unsigned sm_base = (unsigned)(uintptr_t)(void*)smem;

    floatx4 acc[8][4];
    #pragma unroll
    for (int mi = 0; mi < 8; ++mi)
        #pragma unroll
        for (int ni = 0; ni < 4; ++ni)
            acc[mi][ni] = (floatx4){0.f, 0.f, 0.f, 0.f};

    bf16x8 af[4], bfr[4];

#define DSREAD(dst, addr) \
    asm volatile("ds_read_b128 %0, %1" : "=v"(dst) : "v"(addr))

    // A frags: 4 reads at (kk base abK) + mh*8KB + mi*2KB
#define READ_A(AS, abK, mh) do {                                              \
    _Pragma("unroll")                                                         \
    for (int mi = 0; mi < 4; ++mi)                                            \
        DSREAD(af[mi], sm_base + ABYTE(AS) + (abK) + (mh) * 8192u + mi * 2048u); \
    } while (0)

#define READ_B(BS, bbK) do {                                                  \
    _Pragma("unroll")                                                         \
    for (int ni = 0; ni < 4; ++ni)                                            \
        DSREAD(bfr[ni], sm_base + BBYTE(BS) + (bbK) + ni * 2048u);            \
    } while (0)

    // 4 global_load_lds per thread per A-stage / per B-stage (32 KB each)
#define STAGE_A(dstS, kb) do {                                                \
    _Pragma("unroll")                                                         \
    for (int j = 0; j < 4; ++j) {                                             \
        int slot = j * 512 + tid;              /* 2048: 256 rows x 8 octets */ \
        int m = slot >> 3;                                                    \
        int oct = (slot & 7) ^ (m & 7);                                       \
        async_load16(smem + (ABYTE(dstS) >> 1) + slot * 8,                    \
                     xb + (size_t)m * IDIM + (kb) * MS + oct * 8);            \
    } } while (0)

    // block index == j for slot = j*512+tid (n = slot>>3, n>>6 == j)
#define STAGE_B(dstS, tt) do {                                                \
    _Pragma("unroll")                                                         \
    for (int j = 0; j < 4; ++j) {                                             \
        int q = __shfl(pv, j * 16 + (tt));                                    \
        int slot = j * 512 + tid;                                             \
        int n = slot >> 3;                                                    \
        int oct = (slot & 7) ^ (n & 7);                                       \
        async_load16(smem + (BBYTE(dstS) >> 1) + slot * 8,                    \
                     bt + (size_t)q * (MS * MS) + (n & 63) * MS + oct * 8);   \
    } } while (0)

#define MFMA16(mh) do {                                                       \
    __builtin_amdgcn_s_setprio(1);                                            \
    _Pragma("unroll")                                                         \
    for (int mi = 0; mi < 4; ++mi)                                            \
        _Pragma("unroll")                                                     \
        for (int ni = 0; ni < 4; ++ni)                                        \
            acc[(mh) * 4 + mi][ni] = __builtin_amdgcn_mfma_f32_16x16x32_bf16( \
                af[mi], bfr[ni], acc[(mh) * 4 + mi][ni], 0, 0, 0);            \
    __builtin_amdgcn_s_setprio(0); } while (0)

#define LGKM0_FENCE() do {                                                    \
    asm volatile("s_waitcnt lgkmcnt(0)" ::: "memory");                        \
    __builtin_amdgcn_sched_barrier(0); } while (0)

    // one K-tile = 4 m201-style phases; boundary wait WN (<0 = skip)
#define TILE(t, AS, BS, AN, BN2, STA, STB, WN) do {                           \
    /* phase 0: kk0,mh0 ; issue A(t+1) */                                     \
    READ_B(BS, b_b0); READ_A(AS, a_b0, 0);                                    \
    if (STA) STAGE_A(AN, kb0 + (t) + 1);                                      \
    __builtin_amdgcn_s_barrier();                                             \
    LGKM0_FENCE();                                                            \
    MFMA16(0);                                                                \
    __builtin_amdgcn_s_barrier();                                             \
    /* phase 1: kk0,mh1 ; issue B(t+2) */                                     \
    READ_A(AS, a_b0, 1);                                                      \
    if (STB) STAGE_B(BN2, (t) + 2);                                           \
    __builtin_amdgcn_s_barrier();                                             \
    LGKM0_FENCE();                                                            \
    MFMA16(1);                                                                \
    __builtin_amdgcn_s_barrier();                                             \
    /* phase 2: kk1,mh0 */                                                    \
    READ_B(BS, b_b1); READ_A(AS, a_b1, 0);                                    \
    __builtin_amdgcn_s_barrier();                                             \
    LGKM0_FENCE();                                                            \
    MFMA16(0);                                                                \
    __builtin_amdgcn_s_barrier();                                             \
    /* phase 3: kk1,mh1 ; counted boundary wait */                            \
    READ_A(AS, a_b1, 1);                                                      \
    __builtin_amdgcn_s_barrier();                                             \
    LGKM0_FENCE();                                                            \
    MFMA16(1);                                                                \
    if ((WN) >= 0) __builtin_amdgcn_s_waitcnt(WAITCNT_VM((WN) & 63));         \
    __builtin_amdgcn_s_barrier();                                             \
    } while (0)

    // prologue: queue = [A0x4, B0x4, B1x4]; vmcnt(4) retires A0,B0; B1 flies
    STAGE_A(0, kb0);
    STAGE_B(0, 0);
    STAGE_B(1, 1);
    __builtin_amdgcn_s_waitcnt(WAITCNT_VM(4));
    __builtin_amdgcn_sched_barrier(0);
    __builtin_amdgcn_s_barrier();

    // tiles 0..11: 6-tile unroll x2 (A slot t&1, B slot t%3); 12..15 peeled
    #pragma unroll 1
    for (int t6 = 0; t6 < 12; t6 += 6) {
        TILE(t6 + 0, 0, 0, 1, 2, 1, 1, 4);
        TILE(t6 + 1, 1, 1, 0, 0, 1, 1, 4);
        TILE(t6 + 2, 0, 2, 1, 1, 1, 1, 4);
        TILE(t6 + 3, 1, 0, 0, 2, 1, 1, 4);
        TILE(t6 + 4, 0, 1, 1, 0, 1, 1, 4);
        TILE(t6 + 5, 1, 2, 0, 1, 1, 1, 4);
    }
    TILE(12, 0, 0, 1, 2, 1, 1, 4);
    TILE(13, 1, 1, 0, 0, 1, 1, 4);    // stages A14->0, B15->0
    TILE(14, 0, 2, 1, 0, 1, 0, 0);    // stages A15->1; drain [B15,A15]
    TILE(15, 1, 0, 0, 0, 0, 0, -1);   // nothing outstanding

    // epilogue: C/D layout col = lane&15, row = quad*4 + r
    float* out = partial + (size_t)ks * ((size_t)BATCH * ODIM);
    #pragma unroll
    for (int mi8 = 0; mi8 < 8; ++mi8)
        #pragma unroll
        for (int ni = 0; ni < 4; ++ni)
            #pragma unroll
            for (int r = 0; r < 4; ++r) {
                int rowg = wrow * 128 + mi8 * 16 + quad * 4 + r;
                int colg = nt * BN + wcol * 64 + ni * 16 + row;
                out[(size_t)rowg * ODIM + colg] = acc[mi8][ni][r];
            }
}

// ---- kernel 3: sum KSPLIT partials + bias ----
__global__ void k_reduce_bias(const float* __restrict__ partial,
                              const float* __restrict__ bias,
                              float* __restrict__ out) {
    int t = blockIdx.x * 256 + threadIdx.x;
    const float4* b4 = (const float4*)bias;
    float4 c = b4[t & (ODIM / 4 - 1)];
    float4 r = {c.x, c.y, c.z, c.w};
    #pragma unroll
    for (int k = 0; k < KSPLIT; ++k) {
        const float4* p = (const float4*)(partial + (size_t)k * BATCH * ODIM);
        float4 a = p[t];
        r.x += a.x; r.y += a.y; r.z += a.z; r.w += a.w;
    }
    ((float4*)out)[t] = r;
}

extern "C" void kernel_launch(void* const* d_in, const int* in_sizes, int n_in,
                              void* d_out, int out_size, void* d_ws, size_t ws_size,
                              hipStream_t stream) {
    const float* x      = (const float*)d_in[0];
    const float* blocks = (const float*)d_in[1];
    const float* bias   = (const float*)d_in[2];
    const int*   parts  = (const int*)d_in[3];
    float* out = (float*)d_out;

    char* ws = (char*)d_ws;
    unsigned short* xb      = (unsigned short*)ws;                      // 4 MB
    unsigned short* btb     = (unsigned short*)(ws + (4u << 20));       // 8 MB
    int*            pTr     = (int*)(ws + (12u << 20));                 // 64 KB
    float*          partial = (float*)(ws + (13u << 20));               // 64 MB (ks=8)

    // allow 160 KB dynamic LDS (full CU allotment; host-side, graph-capture safe)
    static bool attr_set = false;
    if (!attr_set) {
        hipFuncSetAttribute((const void*)k_mosaic_gemm,
                            hipFuncAttributeMaxDynamicSharedMemorySize, 160 * 1024);
        attr_set = true;
    }

    k_convert<<<NB + XCONV_BLKS + PT_BLKS, 256, 0, stream>>>(x, blocks, parts, xb, btb, pTr);
    k_mosaic_gemm<<<dim3(KSPLIT, ODIM / BN), 512, 160 * 1024, stream>>>(xb, btb, pTr, partial);
    k_reduce_bias<<<(BATCH * ODIM) / (256 * 4), 256, 0, stream>>>(partial, bias, out);
}

// Round 5
// 135.920 us; speedup vs baseline: 1.0539x; 1.0539x over previous
//
#include <hip/hip_runtime.h>
#include <stdint.h>

#define BATCH 256
#define IDIM  8192
#define ODIM  8192
#define MS    64
#define IC    128
#define OC    128
#define NB    1024

// GEMM geometry: 256x256 tile, BK=64, 8 waves (2M x 4N), wave tile 128x64
#define BM 256
#define BN 256
#define KSPLIT 8
#define KT (IC / KSPLIT)           // 16 K-tiles per workgroup

// LDS: A double-buffer only, 2 x 32KB = 64 KB (ushort offsets). B never touches LDS.
#define ABUF(s) ((s) * 16384)

typedef __bf16 bf16x8 __attribute__((ext_vector_type(8)));
typedef float  floatx4 __attribute__((ext_vector_type(4)));

// s_waitcnt imm: vmcnt[3:0]|[15:14], expcnt/lgkmcnt = don't-care
#define WAITCNT_VM(n) ((((n) & 15) | (((n) >> 4) << 14)) | 0x70 | 0xF00)

__device__ __forceinline__ void async_load16(unsigned short* lds_p, const unsigned short* g_p) {
    __builtin_amdgcn_global_load_lds(
        (const __attribute__((address_space(1))) unsigned int*)g_p,
        (__attribute__((address_space(3))) unsigned int*)lds_p,
        16, 0, 0);
}

__device__ __forceinline__ unsigned short f32_to_bf16(float f) {
    unsigned int u = __float_as_uint(f);
    u += 0x7FFFu + ((u >> 16) & 1u);
    return (unsigned short)(u >> 16);
}

// ---- kernel 1: blocks -> bf16 [b][c][r] | x -> bf16 row-major | parts -> pT[ob][ib] ----
#define XCONV_BLKS 1024
#define PT_BLKS 64
__global__ void k_convert(const float* __restrict__ x, const float* __restrict__ blocks,
                          const int* __restrict__ parts,
                          unsigned short* __restrict__ xb, unsigned short* __restrict__ bt,
                          int* __restrict__ pT) {
    __shared__ float tile[MS][MS + 1];
    int b = blockIdx.x;
    if (b < NB) {
        const float4* src4 = (const float4*)(blocks + (size_t)b * MS * MS);
        unsigned short* dst = bt + (size_t)b * MS * MS;
        #pragma unroll
        for (int i = 0; i < 4; ++i) {
            int slot = i * 256 + threadIdx.x;
            int r = slot >> 4, c4 = (slot & 15) * 4;
            float4 v = src4[slot];
            tile[r][c4 + 0] = v.x; tile[r][c4 + 1] = v.y;
            tile[r][c4 + 2] = v.z; tile[r][c4 + 3] = v.w;
        }
        __syncthreads();
        #pragma unroll
        for (int i = 0; i < 2; ++i) {
            int slot = i * 256 + threadIdx.x;
            int c = slot >> 3, o = slot & 7;
            union { unsigned short s[8]; uint4 v; } u;
            #pragma unroll
            for (int j = 0; j < 8; ++j) u.s[j] = f32_to_bf16(tile[o * 8 + j][c]);
            *(uint4*)(dst + c * MS + o * 8) = u.v;        // bt[b][c][r] = [b][n][k]
        }
    } else if (b < NB + XCONV_BLKS) {
        int t = (b - NB) * 256 + threadIdx.x;
        const float4* x4 = (const float4*)x;
        float4 a = x4[2 * t], bb = x4[2 * t + 1];
        union { unsigned short s[8]; uint4 v; } u;
        u.s[0] = f32_to_bf16(a.x);  u.s[1] = f32_to_bf16(a.y);
        u.s[2] = f32_to_bf16(a.z);  u.s[3] = f32_to_bf16(a.w);
        u.s[4] = f32_to_bf16(bb.x); u.s[5] = f32_to_bf16(bb.y);
        u.s[6] = f32_to_bf16(bb.z); u.s[7] = f32_to_bf16(bb.w);
        ((uint4*)xb)[t] = u.v;
    } else {
        int t = (b - NB - XCONV_BLKS) * 256 + threadIdx.x;   // 16384
        int oc = t >> 7, ic = t & 127;
        pT[t] = parts[ic * OC + oc];                          // pT[ob][ib]
    }
}

// ---- kernel 2: GEMM 256x256, 8 waves, wave tile 128x64.
//      A: LDS dbuf(2) via global_load_lds, XOR-swizzled (verified 0 conflicts).
//      B: NO LDS — each wave's 64-col band == one 64x64 block, so B frags load
//      straight from global into registers (SGPR base via readfirstlane(shfl)).
//      Two 16-reg B banks: bk0 holds kk0-half, bk1 holds kk1-half.
//        tile top : issue B(t).kk1 -> bk1        (used 2nd half of tile t)
//        tile mid : issue B(t+1).kk0 -> bk0      (used 1st half of tile t+1)
//      Manual vmcnt only guards A; vm retirement is in-order so vmcnt(12) is
//      safe regardless of compiler-inserted B-reg waits.
//      Per-tile DS traffic drops 256KB -> 160KB (B writes+reads deleted).
extern __shared__ unsigned short smem[];   // 64 KB dynamic

__global__ __launch_bounds__(512, 2)
void k_mosaic_gemm(const unsigned short* __restrict__ xb,
                   const unsigned short* __restrict__ bt,
                   const int* __restrict__ pT,
                   float* __restrict__ partial) {
    const int tid  = threadIdx.x;
    const int lane = tid & 63;
    const int wave = tid >> 6;
    const int wrow = wave >> 2;      // 0..1 : 128-row band
    const int wcol = wave & 3;       // 0..3 : 64-col band == one module block
    const int ks = blockIdx.x;       // 0..7  (linear%8 -> one K-split per XCD)
    const int nt = blockIdx.y;       // 0..31

    const int ob0 = nt * 4;          // 4 output-blocks per 256-col tile
    const int kb0 = ks * KT;         // global K-tile base

    const int row  = lane & 15;
    const int quad = lane >> 4;

    // lane (quad,row) holds block id for ob=ob0+quad, ib=kb0+row
    int pv = pT[(ob0 + quad) * IC + kb0 + row];

    // A frag LDS offsets (ushort units) — verified r2/r3
    const int swz0 = ((quad)     ^ (row & 7)) << 3;    // kk0: octets 0..3
    const int swz1 = ((quad + 4) ^ (row & 7)) << 3;    // kk1: octets 4..7
    const int a_b0 = (wrow * 128 + row) * MS + swz0;
    const int a_b1 = (wrow * 128 + row) * MS + swz1;

    // per-lane B byte-offset within a block: n_local = ni*16+row, k-oct = quad
    // byte = n_local*128 + quad*16 (+ ni*2048 imm + kk*64 imm)
    const int b_off = row * (MS * 2) + quad * 16;

    floatx4 acc[8][4];
    #pragma unroll
    for (int mi = 0; mi < 8; ++mi)
        #pragma unroll
        for (int ni = 0; ni < 4; ++ni)
            acc[mi][ni] = (floatx4){0.f, 0.f, 0.f, 0.f};

    bf16x8 af[4];
    bf16x8 bk0[4], bk1[4];   // B quad-banks: kk0-half / kk1-half

    // 4 global_load_lds per thread per A-stage (32 KB)
#define STAGE_A(dstS, kb) do {                                                \
    _Pragma("unroll")                                                         \
    for (int j = 0; j < 4; ++j) {                                             \
        int slot = j * 512 + tid;              /* 2048: 256 rows x 8 octets */ \
        int m = slot >> 3;                                                    \
        int oct = (slot & 7) ^ (m & 7);                                       \
        async_load16(smem + ABUF(dstS) + slot * 8,                            \
                     xb + (size_t)m * IDIM + (kb) * MS + oct * 8);            \
    } } while (0)

    // 4 global_load_dwordx4 -> one B kk-half for this wave's block at ib=tt
#define LOADB(dstB, tt, kkh) do {                                             \
    int q = __builtin_amdgcn_readfirstlane(__shfl(pv, wcol * 16 + (tt)));     \
    const char* bq = (const char*)(bt + (size_t)q * (MS * MS)) + b_off        \
                     + (kkh) * 64;                                            \
    _Pragma("unroll")                                                         \
    for (int ni = 0; ni < 4; ++ni)                                            \
        dstB[ni] = *(const bf16x8*)(bq + ni * 2048);                          \
    } while (0)

#define LOAD_A(S, abase, mh) do {                                             \
    _Pragma("unroll")                                                         \
    for (int mi = 0; mi < 4; ++mi)                                            \
        af[mi] = *(const bf16x8*)(smem + ABUF(S) + (abase) + (mh) * 4096 + mi * 1024); \
    } while (0)

#define MFMA16(mh, BB) do {                                                   \
    _Pragma("unroll")                                                         \
    for (int mi = 0; mi < 4; ++mi)                                            \
        _Pragma("unroll")                                                     \
        for (int ni = 0; ni < 4; ++ni)                                        \
            acc[(mh) * 4 + mi][ni] = __builtin_amdgcn_mfma_f32_16x16x32_bf16( \
                af[mi], BB[ni], acc[(mh) * 4 + mi][ni], 0, 0, 0);             \
    } while (0)

    // one K-tile. AS: compute A slot; AN: stage A slot for t+1.
    // STA: stage A(t+1)?  MIDB: mid-load B(t+1).kk0?  WN: top vmcnt.
#define TILE(t, AS, AN, STA, MIDB, WN) do {                                   \
    if (STA) STAGE_A(AN, kb0 + (t) + 1);                                      \
    LOADB(bk1, (t), 1);                                                       \
    __builtin_amdgcn_sched_barrier(0);                                        \
    __builtin_amdgcn_s_waitcnt(WAITCNT_VM(WN));                               \
    __builtin_amdgcn_s_barrier();                                             \
    __builtin_amdgcn_sched_barrier(0);                                        \
    LOAD_A(AS, a_b0, 0); MFMA16(0, bk0);                                      \
    LOAD_A(AS, a_b0, 1); MFMA16(1, bk0);                                      \
    __builtin_amdgcn_sched_barrier(0);                                        \
    if (MIDB) LOADB(bk0, (t) + 1, 0);                                         \
    __builtin_amdgcn_sched_barrier(0);                                        \
    LOAD_A(AS, a_b1, 0); MFMA16(0, bk1);                                      \
    LOAD_A(AS, a_b1, 1); MFMA16(1, bk1);                                      \
    __builtin_amdgcn_sched_barrier(0);                                        \
    __builtin_amdgcn_s_barrier();                                             \
    __builtin_amdgcn_sched_barrier(0);                                        \
    } while (0)

    // prologue: A0 stage + B0.kk0. Tile-0 top then matches steady state:
    // queue at top-vmcnt = [A(t)4, B(t)kk0 4, A(t+1)4, B(t)kk1 4] -> vmcnt(12)
    // retires A(t) (in-order); compiler auto-waits the B regs at first use.
    STAGE_A(0, kb0);
    LOADB(bk0, 0, 0);

    #pragma unroll 1
    for (int t2 = 0; t2 < 14; t2 += 2) {
        TILE(t2,     0, 1, 1, 1, 12);
        TILE(t2 + 1, 1, 0, 1, 1, 12);
    }
    TILE(14, 0, 1, 1, 1, 12);   // stages A15; mid-loads B15.kk0
    TILE(15, 1, 0, 0, 0, 8);    // queue=[A15,B15kk0,B15kk1]: vmcnt(8) retires A15

    // epilogue: C/D layout col = lane&15, row = quad*4 + r
    float* out = partial + (size_t)ks * ((size_t)BATCH * ODIM);
    #pragma unroll
    for (int mi8 = 0; mi8 < 8; ++mi8)
        #pragma unroll
        for (int ni = 0; ni < 4; ++ni)
            #pragma unroll
            for (int r = 0; r < 4; ++r) {
                int rowg = wrow * 128 + mi8 * 16 + quad * 4 + r;
                int colg = nt * BN + wcol * 64 + ni * 16 + row;
                out[(size_t)rowg * ODIM + colg] = acc[mi8][ni][r];
            }
}

// ---- kernel 3: sum KSPLIT partials + bias ----
__global__ void k_reduce_bias(const float* __restrict__ partial,
                              const float* __restrict__ bias,
                              float* __restrict__ out) {
    int t = blockIdx.x * 256 + threadIdx.x;
    const float4* b4 = (const float4*)bias;
    float4 c = b4[t & (ODIM / 4 - 1)];
    float4 r = {c.x, c.y, c.z, c.w};
    #pragma unroll
    for (int k = 0; k < KSPLIT; ++k) {
        const float4* p = (const float4*)(partial + (size_t)k * BATCH * ODIM);
        float4 a = p[t];
        r.x += a.x; r.y += a.y; r.z += a.z; r.w += a.w;
    }
    ((float4*)out)[t] = r;
}

extern "C" void kernel_launch(void* const* d_in, const int* in_sizes, int n_in,
                              void* d_out, int out_size, void* d_ws, size_t ws_size,
                              hipStream_t stream) {
    const float* x      = (const float*)d_in[0];
    const float* blocks = (const float*)d_in[1];
    const float* bias   = (const float*)d_in[2];
    const int*   parts  = (const int*)d_in[3];
    float* out = (float*)d_out;

    char* ws = (char*)d_ws;
    unsigned short* xb      = (unsigned short*)ws;                      // 4 MB
    unsigned short* btb     = (unsigned short*)(ws + (4u << 20));       // 8 MB
    int*            pTr     = (int*)(ws + (12u << 20));                 // 64 KB
    float*          partial = (float*)(ws + (13u << 20));               // 64 MB (ks=8)

    static bool attr_set = false;
    if (!attr_set) {
        hipFuncSetAttribute((const void*)k_mosaic_gemm,
                            hipFuncAttributeMaxDynamicSharedMemorySize, 64 * 1024);
        attr_set = true;
    }

    k_convert<<<NB + XCONV_BLKS + PT_BLKS, 256, 0, stream>>>(x, blocks, parts, xb, btb, pTr);
    k_mosaic_gemm<<<dim3(KSPLIT, ODIM / BN), 512, 64 * 1024, stream>>>(xb, btb, pTr, partial);
    k_reduce_bias<<<(BATCH * ODIM) / (256 * 4), 256, 0, stream>>>(partial, bias, out);
}